// Round 10
// baseline (272.271 us; speedup 1.0000x reference)
//
#include <hip/hip_runtime.h>
#include <stdint.h>

typedef unsigned short u16;
typedef __bf16 bf16x8 __attribute__((ext_vector_type(8)));
typedef float f32x4 __attribute__((ext_vector_type(4)));
typedef float f32x16 __attribute__((ext_vector_type(16)));
typedef unsigned short u16x8 __attribute__((ext_vector_type(8)));
typedef unsigned short u16x4 __attribute__((ext_vector_type(4)));

#define HD 16
#define BB 4
#define SS 2048
#define DD 1024
#define DH 64

#if __has_builtin(__builtin_amdgcn_exp2f)
#define EXP2(x) __builtin_amdgcn_exp2f(x)
#else
#define EXP2(x) exp2f(x)
#endif

__device__ __forceinline__ u16 f2bf(float f) {
  union { float f; uint32_t u; } v; v.f = f;
  uint32_t u = v.u;
  return (u16)((u + 0x7FFFu + ((u >> 16) & 1u)) >> 16);  // RNE, no NaN in data
}

// native converter for hot paths (single v_cvt, RNE)
__device__ __forceinline__ u16 bfbits(float f) {
  union { __bf16 h; u16 u; } c;
  c.h = (__bf16)f;
  return c.u;
}

// pack two f32 -> u32 of 2 bf16 (lo = first arg), single instruction.
__device__ __forceinline__ uint32_t cvtpk(float lo, float hi) {
  uint32_t r;
  asm("v_cvt_pk_bf16_f32 %0, %1, %2" : "=v"(r) : "v"(lo), "v"(hi));
  return r;
}

__device__ __forceinline__ void gl2lds16(const void* g, void* l) {
  __builtin_amdgcn_global_load_lds(
      (const __attribute__((address_space(1))) void*)g,
      (__attribute__((address_space(3))) void*)l, 16, 0, 0);
}

// ---------------- cast x (fp32 -> bf16), 4 elems/thread ----------------
__global__ __launch_bounds__(256) void cast_x_kernel(const float* __restrict__ src,
                                                     u16* __restrict__ dst, int n4) {
  int i = blockIdx.x * 256 + threadIdx.x;
  if (i >= n4) return;
  float4 v = ((const float4*)src)[i];
  u16x4 o;
  o.x = f2bf(v.x); o.y = f2bf(v.y); o.z = f2bf(v.z); o.w = f2bf(v.w);
  ((u16x4*)dst)[i] = o;
}

// ------ transpose + cast all 4 weights in one launch: blockIdx.z picks the weight ------
__global__ __launch_bounds__(256) void wtrans4_kernel(const float* __restrict__ WQ,
                                                      const float* __restrict__ WK,
                                                      const float* __restrict__ WV,
                                                      const float* __restrict__ WO,
                                                      u16* __restrict__ wcat,
                                                      u16* __restrict__ wot, float qscale) {
  __shared__ u16 tile[64][65];
  const int z = blockIdx.z;
  const float* src = (z == 0) ? WQ : (z == 1) ? WK : (z == 2) ? WV : WO;
  u16* dst = (z < 3) ? wcat + (size_t)z * 1024 * 1024 : wot;
  const float scale = (z == 0) ? qscale : 1.0f;
  const int bx = blockIdx.x * 64;  // src col (n)
  const int by = blockIdx.y * 64;  // src row (k)
  const int t = threadIdx.x;
  const int c = t & 63, r0 = t >> 6;
#pragma unroll
  for (int r = r0; r < 64; r += 4)
    tile[r][c] = f2bf(src[(size_t)(by + r) * 1024 + bx + c] * scale);
  __syncthreads();
#pragma unroll
  for (int r = r0; r < 64; r += 4)
    dst[(size_t)(bx + r) * 1024 + by + c] = tile[c][r];
}

// ------------- V transpose: qkv[b*S+s][2048 + h*64 + d] -> vt[((b*16+h)*64+d)][s] -------------
__global__ __launch_bounds__(256) void vtrans_kernel(const u16* __restrict__ qkv,
                                                     u16* __restrict__ vt) {
  __shared__ u16 tile[64][65];
  const int s0 = blockIdx.x * 64;
  const int h = blockIdx.y;
  const int b = blockIdx.z;
  const int t = threadIdx.x;
  const int c = t & 63, r0 = t >> 6;
#pragma unroll
  for (int r = r0; r < 64; r += 4)
    tile[r][c] = qkv[(size_t)(b * SS + s0 + r) * 3072 + 2048 + h * DH + c];
  __syncthreads();
#pragma unroll
  for (int r = r0; r < 64; r += 4)
    vt[((size_t)(b * HD + h) * DH + r) * SS + s0 + c] = tile[c][r];
}

// ---------------- NT GEMM, BK=64, 128xBN tile, 16x16x32 MFMA ----------------
// R20: templated on BN. Budget reconstruction says AO (M=8192,N=1024) at
// BN=128 had grid 512 = EXACTLY 2 blocks/CU — below the ~3/CU the 2-barrier
// structure needs for implicit wave-level stage/compute overlap (m114); AO
// was occupancy-starved (~300 TF est). BN=64 for AO: grid 16x64 = 1024 blocks
// = 4 blocks/CU (LDS 24 KB -> 6/CU cap), acc 32 VGPR. QKV keeps BN=128
// (1536 blocks = 5-6/CU, already overlapped; <=70 us hard-bounded by top-5).
// BN=128 instantiation is identical to the proven R19 kernel.
template <int OUT_BF16, int BN>
__global__ __launch_bounds__(256) void gemm_nt_kernel(const u16* __restrict__ A,
                                                      const u16* __restrict__ Bt,
                                                      void* __restrict__ Cv,
                                                      int M, int N, int K) {
  constexpr int JT = BN / 32;  // j-tiles per wave (wave covers BN/2 cols)
  __shared__ __attribute__((aligned(16))) u16 As[128 * 64];  // 16 KB
  __shared__ __attribute__((aligned(16))) u16 Bs[BN * 64];   // BN/8 KB
  const int t = threadIdx.x;
  const int lane = t & 63;
  const int w = t >> 6;
  const int m0 = blockIdx.y * 128;
  const int n0 = blockIdx.x * BN;

  f32x4 acc[4][JT] = {};

  const int srow = t >> 3;            // staging row within pass (0..31)
  const int cpos = t & 7;             // chunk slot 0..7
  const int scc = cpos ^ (srow & 7);  // XOR-swizzled chunk (pass-invariant)
  const int wm = (w >> 1) * 64;
  const int wn = (w & 1) * (BN / 2);
  const int lr = lane & 15;   // frag row/col
  const int kg = lane >> 4;   // 0..3: which 8-elem k-chunk of the 32-wide instr K

  for (int k0 = 0; k0 < K; k0 += 64) {
#pragma unroll
    for (int p = 0; p < 4; ++p) {
      int row = p * 32 + srow;
      gl2lds16(A + (size_t)(m0 + row) * K + k0 + scc * 8, (char*)As + p * 4096 + w * 1024);
    }
#pragma unroll
    for (int p = 0; p < BN / 32; ++p) {
      int row = p * 32 + srow;
      gl2lds16(Bt + (size_t)(n0 + row) * K + k0 + scc * 8, (char*)Bs + p * 4096 + w * 1024);
    }
    __syncthreads();

#pragma unroll
    for (int ks = 0; ks < 2; ++ks) {  // 2 x K=32
      bf16x8 af[4], bfr[JT];
#pragma unroll
      for (int i = 0; i < 4; ++i) {
        int ra = wm + i * 16 + lr;
        af[i] = *(const bf16x8*)(As + ra * 64 + (((ks * 4 + kg) ^ (ra & 7)) * 8));
      }
#pragma unroll
      for (int j = 0; j < JT; ++j) {
        int rb = wn + j * 16 + lr;
        bfr[j] = *(const bf16x8*)(Bs + rb * 64 + (((ks * 4 + kg) ^ (rb & 7)) * 8));
      }
#pragma unroll
      for (int i = 0; i < 4; ++i)
#pragma unroll
        for (int j = 0; j < JT; ++j)
          acc[i][j] = __builtin_amdgcn_mfma_f32_16x16x32_bf16(af[i], bfr[j], acc[i][j], 0, 0, 0);
    }
    __syncthreads();
  }

  // C/D: col = lane&15 (lr), row = kg*4 + rg (m89 HW-verified)
#pragma unroll
  for (int i = 0; i < 4; ++i)
#pragma unroll
    for (int j = 0; j < JT; ++j)
#pragma unroll
      for (int rg = 0; rg < 4; ++rg) {
        int gr = m0 + wm + i * 16 + kg * 4 + rg;
        int gc = n0 + wn + j * 16 + lr;
        float v = acc[i][j][rg];
        if (OUT_BF16)
          ((u16*)Cv)[(size_t)gr * N + gc] = f2bf(v);
        else
          ((float*)Cv)[(size_t)gr * N + gc] = v;
      }
}

// ---------------- flash attention: per (qtile256, h, b) ----------------
// R18 (FROZEN at 70.4 us): R15 + single-syncthreads double-buffer. MFMA 42%
// + VALU 47% = ~89% combined issue -> near issue saturation; more TLP can't
// add issue slots (split-K rejected: merge traffic > the 11% residue). Parked.
__global__ __launch_bounds__(256, 2) void attn_kernel(const u16* __restrict__ qkv,
                                                      const u16* __restrict__ vt,
                                                      u16* __restrict__ ctx) {
  // dbuf layout (bytes): buf s at s*16384: K[64][64] @ +0, V^T[64][64] @ +8192.
  // Epilogue reuses SMEM as Es[256][72] = 36864 B.
  __shared__ __attribute__((aligned(16))) u16 SMEM[18432];  // 36.9 KB

  const int t = threadIdx.x;
  const int lane = t & 63;
  const int w = t >> 6;
  const int q0 = blockIdx.x * 256;
  const int h = blockIdx.y;
  const int b = blockIdx.z;

  const int srow = t >> 3;  // staging row (0..31 per pass)
  const int cpos = t & 7;
  const size_t qkv_row0 = (size_t)(b * SS) * 3072;
  const size_t vtbase = ((size_t)(b * HD + h) * DH) * SS;

  const int l31 = lane & 31;
  const int kh = lane >> 5;
  // pi: swap bits 2<->3 (C-row rho -> key), so regs line up as PV B-frags
  const int p31 = (l31 & 19) | ((l31 & 4) << 1) | ((l31 & 8) >> 1);
  // per-lane sigma bases (tt/dt add ^4 via the r>>5 term)
  const int sK0 = (p31 & 3) | ((((p31 >> 2) ^ (p31 >> 3)) & 1) << 2);
  const int sV0 = (l31 & 3) | ((((l31 >> 2) ^ (l31 >> 3)) & 1) << 2);

  // stage tile (64 keys at tile*64) into buffer bufsel (4 gl2lds per wave).
  auto stage = [&](int tile, int bufsel) {
    char* Kb = (char*)SMEM + bufsel * 16384;
    const int kk0 = tile * 64;
#pragma unroll
    for (int p = 0; p < 2; ++p) {
      int r = p * 32 + srow;
      int sg = (r & 3) | ((((r >> 2) ^ (r >> 3) ^ (r >> 5)) & 1) << 2);
      int cc = cpos ^ sg;
      gl2lds16(qkv + qkv_row0 + (size_t)(kk0 + r) * 3072 + 1024 + h * DH + cc * 8,
               Kb + p * 4096 + w * 1024);
      gl2lds16(vt + vtbase + (size_t)r * SS + kk0 + cc * 8,
               Kb + 8192 + p * 4096 + w * 1024);
    }
  };

  stage(0, 0);  // prologue: tile 0 -> buf 0

  // Q frags (loaded once): q = q0 + w*64 + qq*32 + l31, d = ks*16 + kh*8 + {0..7}.
  // WQ carries 1/sqrt(D)*log2(e).
  bf16x8 aq[2][4];
#pragma unroll
  for (int qq = 0; qq < 2; ++qq)
#pragma unroll
    for (int ks = 0; ks < 4; ++ks)
      aq[qq][ks] = *(const bf16x8*)(qkv + qkv_row0 +
                                    (size_t)(q0 + w * 64 + qq * 32 + l31) * 3072 +
                                    h * DH + ks * 16 + kh * 8);

  f32x16 ot[2][2] = {};          // ot[qq][dt][r]: d = dt*32+(r&3)+8*(r>>2)+4*kh
  float l_p0 = 0.f, l_p1 = 0.f;  // per-lane partial sum of 2^s, per qq

  __syncthreads();  // tile 0 staged (drains prologue loads)

  for (int tile = 0; tile < SS / 64; ++tile) {
    const int cur = tile & 1;

    // prefetch next tile into the other buffer; its latency hides under this
    // tile's compute, and the END-of-iter barrier drains it (cheap by then).
    if (tile + 1 < SS / 64) stage(tile + 1, cur ^ 1);

    const u16* Ks = SMEM + cur * 8192;  // u16 idx: 16384 B per buffer
    const u16* Vs = Ks + 4096;

    // S^T = K Q^T: c2[qq][t][r] = P[key = t*32+16*(r>>3)+8*kh+4*((r>>2)&1)+(r&3)][q]
    // One ak read feeds both qq MFMA.
    f32x16 c2[2][2] = {};
#pragma unroll
    for (int ks = 0; ks < 4; ++ks) {
#pragma unroll
      for (int tt = 0; tt < 2; ++tt) {
        int jr = tt * 32 + p31;
        int slot = (ks * 2 + kh) ^ sK0 ^ (tt << 2);
        bf16x8 ak = *(const bf16x8*)(Ks + jr * 64 + slot * 8);
        c2[0][tt] = __builtin_amdgcn_mfma_f32_32x32x16_bf16(ak, aq[0][ks], c2[0][tt], 0, 0, 0);
        c2[1][tt] = __builtin_amdgcn_mfma_f32_32x32x16_bf16(ak, aq[1][ks], c2[1][tt], 0, 0, 0);
      }
    }

    // P = 2^s in place; per-lane partial l per qq
#pragma unroll
    for (int qq = 0; qq < 2; ++qq)
#pragma unroll
      for (int tt = 0; tt < 2; ++tt)
#pragma unroll
        for (int r = 0; r < 16; ++r)
          c2[qq][tt][r] = EXP2(c2[qq][tt][r]);
    {
      float s0 = 0.f, s1 = 0.f;
#pragma unroll
      for (int r = 0; r < 16; ++r) { s0 += c2[0][0][r]; s0 += c2[0][1][r]; }
#pragma unroll
      for (int r = 0; r < 16; ++r) { s1 += c2[1][0][r]; s1 += c2[1][1][r]; }
      l_p0 += s0; l_p1 += s1;
    }

    // pack P^T B-frags fully in-register: bp[qq][2t+hf].elem[j] = c2[qq][t][8*hf+j]
    union { uint32_t u[4]; bf16x8 b; } bp[2][4];
#pragma unroll
    for (int qq = 0; qq < 2; ++qq)
#pragma unroll
      for (int tt = 0; tt < 2; ++tt)
#pragma unroll
        for (int hf = 0; hf < 2; ++hf)
#pragma unroll
          for (int i = 0; i < 4; ++i)
            bp[qq][tt * 2 + hf].u[i] =
                cvtpk(c2[qq][tt][hf * 8 + 2 * i], c2[qq][tt][hf * 8 + 2 * i + 1]);

    // O^T += V^T P^T  (A = V^T rows = d; one av read feeds both qq MFMA)
#pragma unroll
    for (int ks = 0; ks < 4; ++ks) {
#pragma unroll
      for (int dt = 0; dt < 2; ++dt) {
        int vr = dt * 32 + l31;
        int slot = (ks * 2 + kh) ^ sV0 ^ (dt << 2);
        bf16x8 av = *(const bf16x8*)(Vs + vr * 64 + slot * 8);
        ot[0][dt] = __builtin_amdgcn_mfma_f32_32x32x16_bf16(av, bp[0][ks].b, ot[0][dt], 0, 0, 0);
        ot[1][dt] = __builtin_amdgcn_mfma_f32_32x32x16_bf16(av, bp[1][ks].b, ot[1][dt], 0, 0, 0);
      }
    }

    // single barrier: drains the prefetch (issued a compute-phase ago, so
    // cheap) AND protects buf[cur] before iter t+1 stages into it.
    __syncthreads();
  }

  // epilogue: l across the two kh halves (lanes l, l+32 share q)
  l_p0 += __shfl_xor(l_p0, 32, 64);
  l_p1 += __shfl_xor(l_p1, 32, 64);
  const float inv_l0 = 1.0f / l_p0;
  const float inv_l1 = 1.0f / l_p1;

  // normalize + stage O^T -> Es[256 q][72] (reused SMEM; wave-local rows)
  u16* Es = SMEM;
#pragma unroll
  for (int qq = 0; qq < 2; ++qq) {
    const float il = qq ? inv_l1 : inv_l0;
#pragma unroll
    for (int dt = 0; dt < 2; ++dt)
#pragma unroll
      for (int rq = 0; rq < 4; ++rq) {
        u16x4 pv;
#pragma unroll
        for (int i = 0; i < 4; ++i) pv[i] = bfbits(ot[qq][dt][rq * 4 + i] * il);
        *(u16x4*)(Es + (w * 64 + qq * 32 + l31) * 72 + dt * 32 + rq * 8 + kh * 4) = pv;
      }
  }

  const int rr = lane >> 3;  // 0..7
  const int cc8 = lane & 7;  // 16B chunk
#pragma unroll
  for (int p = 0; p < 8; ++p) {
    int row = w * 64 + p * 8 + rr;
    u16x8 vv = *(const u16x8*)(Es + row * 72 + cc8 * 8);
    *(u16x8*)(ctx + (size_t)(b * SS + q0 + row) * DD + h * DH + cc8 * 8) = vv;
  }
}

extern "C" void kernel_launch(void* const* d_in, const int* in_sizes, int n_in,
                              void* d_out, int out_size, void* d_ws, size_t ws_size,
                              hipStream_t stream) {
  (void)in_sizes; (void)n_in; (void)out_size; (void)ws_size;
  const float* x = (const float*)d_in[0];
  const float* WQ = (const float*)d_in[1];
  const float* WK = (const float*)d_in[2];
  const float* WV = (const float*)d_in[3];
  const float* WO = (const float*)d_in[4];

  char* ws = (char*)d_ws;
  u16* xb = (u16*)ws;            ws += (size_t)8192 * 1024 * 2;   // 16.8 MB (reused as ctx)
  u16* wcat = (u16*)ws;          ws += (size_t)3072 * 1024 * 2;   // 6.3 MB
  u16* wot = (u16*)ws;           ws += (size_t)1024 * 1024 * 2;   // 2.1 MB
  u16* qkv = (u16*)ws;           ws += (size_t)8192 * 3072 * 2;   // 50.3 MB
  u16* vt = (u16*)ws;            ws += (size_t)BB * HD * DH * SS * 2;  // 16.8 MB
  u16* ctx = xb;  // x consumed by QKV GEMM before attention writes ctx

  // 1/sqrt(1024) * log2(e): softmax runs in exp2 domain with scale folded into WQ
  const float QSCALE = 0.03125f * 1.4426950408889634f;

  cast_x_kernel<<<dim3(8192), dim3(256), 0, stream>>>(x, xb, 2097152);
  wtrans4_kernel<<<dim3(16, 16, 4), dim3(256), 0, stream>>>(WQ, WK, WV, WO, wcat, wot, QSCALE);

  gemm_nt_kernel<1, 128><<<dim3(24, 64), dim3(256), 0, stream>>>(xb, wcat, (void*)qkv, 8192, 3072, 1024);
  vtrans_kernel<<<dim3(32, 16, 4), dim3(256), 0, stream>>>(qkv, vt);
  attn_kernel<<<dim3(8, 16, 4), dim3(256), 0, stream>>>(qkv, vt, ctx);
  gemm_nt_kernel<0, 64><<<dim3(16, 64), dim3(256), 0, stream>>>(ctx, wot, d_out, 8192, 1024, 1024);
}

// Round 11
// 259.157 us; speedup vs baseline: 1.0506x; 1.0506x over previous
//
#include <hip/hip_runtime.h>
#include <stdint.h>

typedef unsigned short u16;
typedef __bf16 bf16x8 __attribute__((ext_vector_type(8)));
typedef float f32x4 __attribute__((ext_vector_type(4)));
typedef float f32x16 __attribute__((ext_vector_type(16)));
typedef unsigned short u16x8 __attribute__((ext_vector_type(8)));
typedef unsigned short u16x4 __attribute__((ext_vector_type(4)));

#define HD 16
#define BB 4
#define SS 2048
#define DD 1024
#define DH 64

#if __has_builtin(__builtin_amdgcn_exp2f)
#define EXP2(x) __builtin_amdgcn_exp2f(x)
#else
#define EXP2(x) exp2f(x)
#endif

__device__ __forceinline__ u16 f2bf(float f) {
  union { float f; uint32_t u; } v; v.f = f;
  uint32_t u = v.u;
  return (u16)((u + 0x7FFFu + ((u >> 16) & 1u)) >> 16);  // RNE, no NaN in data
}

// native converter for hot paths (single v_cvt, RNE)
__device__ __forceinline__ u16 bfbits(float f) {
  union { __bf16 h; u16 u; } c;
  c.h = (__bf16)f;
  return c.u;
}

// pack two f32 -> u32 of 2 bf16 (lo = first arg), single instruction.
__device__ __forceinline__ uint32_t cvtpk(float lo, float hi) {
  uint32_t r;
  asm("v_cvt_pk_bf16_f32 %0, %1, %2" : "=v"(r) : "v"(lo), "v"(hi));
  return r;
}

__device__ __forceinline__ void gl2lds16(const void* g, void* l) {
  __builtin_amdgcn_global_load_lds(
      (const __attribute__((address_space(1))) void*)g,
      (__attribute__((address_space(3))) void*)l, 16, 0, 0);
}

// -------- fused prep (R21): cast x (8192 blocks) + transpose 4 weights (1024 blocks) --------
// cast_x and wtrans4 are independent, same block size, previously serialized on
// the stream: one launch instead of two (saves a graph-node gap; hot paths
// untouched). Blocks < 8192: fp32->bf16 cast, 4 elems/thread. Blocks >= 8192:
// 64x64 transpose+cast tile of one of the 4 weights (z = id2>>8).
__global__ __launch_bounds__(256) void prep_kernel(const float* __restrict__ x,
                                                   u16* __restrict__ xb,
                                                   const float* __restrict__ WQ,
                                                   const float* __restrict__ WK,
                                                   const float* __restrict__ WV,
                                                   const float* __restrict__ WO,
                                                   u16* __restrict__ wcat,
                                                   u16* __restrict__ wot, float qscale) {
  __shared__ u16 tile[64][65];
  const int bid = blockIdx.x;
  const int t = threadIdx.x;
  if (bid < 8192) {
    int i = bid * 256 + t;  // n4 = 2097152 = 8192*256 exactly
    float4 v = ((const float4*)x)[i];
    u16x4 o;
    o.x = f2bf(v.x); o.y = f2bf(v.y); o.z = f2bf(v.z); o.w = f2bf(v.w);
    ((u16x4*)xb)[i] = o;
    return;
  }
  const int id2 = bid - 8192;
  const int z = id2 >> 8;
  const float* src = (z == 0) ? WQ : (z == 1) ? WK : (z == 2) ? WV : WO;
  u16* dst = (z < 3) ? wcat + (size_t)z * 1024 * 1024 : wot;
  const float scale = (z == 0) ? qscale : 1.0f;
  const int bx = (id2 & 15) * 64;         // src col (n)
  const int by = ((id2 >> 4) & 15) * 64;  // src row (k)
  const int c = t & 63, r0 = t >> 6;
#pragma unroll
  for (int r = r0; r < 64; r += 4)
    tile[r][c] = f2bf(src[(size_t)(by + r) * 1024 + bx + c] * scale);
  __syncthreads();
#pragma unroll
  for (int r = r0; r < 64; r += 4)
    dst[(size_t)(bx + r) * 1024 + by + c] = tile[c][r];
}

// ------------- V transpose: qkv[b*S+s][2048 + h*64 + d] -> vt[((b*16+h)*64+d)][s] -------------
__global__ __launch_bounds__(256) void vtrans_kernel(const u16* __restrict__ qkv,
                                                     u16* __restrict__ vt) {
  __shared__ u16 tile[64][65];
  const int s0 = blockIdx.x * 64;
  const int h = blockIdx.y;
  const int b = blockIdx.z;
  const int t = threadIdx.x;
  const int c = t & 63, r0 = t >> 6;
#pragma unroll
  for (int r = r0; r < 64; r += 4)
    tile[r][c] = qkv[(size_t)(b * SS + s0 + r) * 3072 + 2048 + h * DH + c];
  __syncthreads();
#pragma unroll
  for (int r = r0; r < 64; r += 4)
    vt[((size_t)(b * HD + h) * DH + r) * SS + s0 + c] = tile[c][r];
}

// ---------------- NT GEMM, BK=64, 128x128 tile, 32x32x16 MFMA ----------------
// R21: exact R18 form restored (best proven: 264.05 us total). Three GEMM
// rounds (R19 shape swap flat, R20 BN=64 regression) establish this structure
// is at its ceiling (~700-800 TF): not conflict-bound (R19), and tile
// shrinking trades reuse for TLP at a net loss (R20). Breaking past needs the
// 8-phase 256-class rewrite (deferred: QKV grid 384 = 1.5 blocks/CU at 128KB
// LDS has a load-imbalance problem at this shape).
template <int OUT_BF16>
__global__ __launch_bounds__(256) void gemm_nt_kernel(const u16* __restrict__ A,
                                                      const u16* __restrict__ Bt,
                                                      void* __restrict__ Cv,
                                                      int M, int N, int K) {
  __shared__ __attribute__((aligned(16))) u16 As[128 * 64];  // 16 KB
  __shared__ __attribute__((aligned(16))) u16 Bs[128 * 64];  // 16 KB
  const int t = threadIdx.x;
  const int lane = t & 63;
  const int w = t >> 6;
  const int m0 = blockIdx.y * 128;
  const int n0 = blockIdx.x * 128;

  f32x16 acc[2][2] = {};

  const int srow = t >> 3;            // staging row within pass (0..31)
  const int cpos = t & 7;             // chunk slot 0..7
  const int scc = cpos ^ (srow & 7);  // XOR-swizzled chunk (pass-invariant)
  const int wm = (w >> 1) * 64;
  const int wn = (w & 1) * 64;
  const int l31 = lane & 31;
  const int kh = lane >> 5;  // 0/1: which 8-wide k-half of the 16-wide instr K

  for (int k0 = 0; k0 < K; k0 += 64) {
#pragma unroll
    for (int p = 0; p < 4; ++p) {
      int row = p * 32 + srow;
      gl2lds16(A + (size_t)(m0 + row) * K + k0 + scc * 8, (char*)As + p * 4096 + w * 1024);
      gl2lds16(Bt + (size_t)(n0 + row) * K + k0 + scc * 8, (char*)Bs + p * 4096 + w * 1024);
    }
    __syncthreads();

#pragma unroll
    for (int ks = 0; ks < 4; ++ks) {  // 4 x K=16
      bf16x8 af[2], bfr[2];
#pragma unroll
      for (int i = 0; i < 2; ++i) {
        int ra = wm + i * 32 + l31;
        af[i] = *(const bf16x8*)(As + ra * 64 + (((ks * 2 + kh) ^ (ra & 7)) * 8));
        int rb = wn + i * 32 + l31;
        bfr[i] = *(const bf16x8*)(Bs + rb * 64 + (((ks * 2 + kh) ^ (rb & 7)) * 8));
      }
#pragma unroll
      for (int i = 0; i < 2; ++i)
#pragma unroll
        for (int j = 0; j < 2; ++j)
          acc[i][j] = __builtin_amdgcn_mfma_f32_32x32x16_bf16(af[i], bfr[j], acc[i][j], 0, 0, 0);
    }
    __syncthreads();
  }

#pragma unroll
  for (int i = 0; i < 2; ++i)
#pragma unroll
    for (int j = 0; j < 2; ++j)
#pragma unroll
      for (int rg = 0; rg < 16; ++rg) {
        int gr = m0 + wm + i * 32 + (rg & 3) + ((rg >> 2) * 8) + 4 * kh;
        int gc = n0 + wn + j * 32 + l31;
        float v = acc[i][j][rg];
        if (OUT_BF16)
          ((u16*)Cv)[(size_t)gr * N + gc] = f2bf(v);
        else
          ((float*)Cv)[(size_t)gr * N + gc] = v;
      }
}

// ---------------- flash attention: per (qtile256, h, b) ----------------
// R18 (FROZEN at 70.4 us): R15 + single-syncthreads double-buffer. MFMA 42%
// + VALU 47% = ~89% combined issue -> near issue saturation. Parked.
__global__ __launch_bounds__(256, 2) void attn_kernel(const u16* __restrict__ qkv,
                                                      const u16* __restrict__ vt,
                                                      u16* __restrict__ ctx) {
  // dbuf layout (bytes): buf s at s*16384: K[64][64] @ +0, V^T[64][64] @ +8192.
  // Epilogue reuses SMEM as Es[256][72] = 36864 B.
  __shared__ __attribute__((aligned(16))) u16 SMEM[18432];  // 36.9 KB

  const int t = threadIdx.x;
  const int lane = t & 63;
  const int w = t >> 6;
  const int q0 = blockIdx.x * 256;
  const int h = blockIdx.y;
  const int b = blockIdx.z;

  const int srow = t >> 3;  // staging row (0..31 per pass)
  const int cpos = t & 7;
  const size_t qkv_row0 = (size_t)(b * SS) * 3072;
  const size_t vtbase = ((size_t)(b * HD + h) * DH) * SS;

  const int l31 = lane & 31;
  const int kh = lane >> 5;
  // pi: swap bits 2<->3 (C-row rho -> key), so regs line up as PV B-frags
  const int p31 = (l31 & 19) | ((l31 & 4) << 1) | ((l31 & 8) >> 1);
  // per-lane sigma bases (tt/dt add ^4 via the r>>5 term)
  const int sK0 = (p31 & 3) | ((((p31 >> 2) ^ (p31 >> 3)) & 1) << 2);
  const int sV0 = (l31 & 3) | ((((l31 >> 2) ^ (l31 >> 3)) & 1) << 2);

  // stage tile (64 keys at tile*64) into buffer bufsel (4 gl2lds per wave).
  auto stage = [&](int tile, int bufsel) {
    char* Kb = (char*)SMEM + bufsel * 16384;
    const int kk0 = tile * 64;
#pragma unroll
    for (int p = 0; p < 2; ++p) {
      int r = p * 32 + srow;
      int sg = (r & 3) | ((((r >> 2) ^ (r >> 3) ^ (r >> 5)) & 1) << 2);
      int cc = cpos ^ sg;
      gl2lds16(qkv + qkv_row0 + (size_t)(kk0 + r) * 3072 + 1024 + h * DH + cc * 8,
               Kb + p * 4096 + w * 1024);
      gl2lds16(vt + vtbase + (size_t)r * SS + kk0 + cc * 8,
               Kb + 8192 + p * 4096 + w * 1024);
    }
  };

  stage(0, 0);  // prologue: tile 0 -> buf 0

  // Q frags (loaded once): q = q0 + w*64 + qq*32 + l31, d = ks*16 + kh*8 + {0..7}.
  // WQ carries 1/sqrt(D)*log2(e).
  bf16x8 aq[2][4];
#pragma unroll
  for (int qq = 0; qq < 2; ++qq)
#pragma unroll
    for (int ks = 0; ks < 4; ++ks)
      aq[qq][ks] = *(const bf16x8*)(qkv + qkv_row0 +
                                    (size_t)(q0 + w * 64 + qq * 32 + l31) * 3072 +
                                    h * DH + ks * 16 + kh * 8);

  f32x16 ot[2][2] = {};          // ot[qq][dt][r]: d = dt*32+(r&3)+8*(r>>2)+4*kh
  float l_p0 = 0.f, l_p1 = 0.f;  // per-lane partial sum of 2^s, per qq

  __syncthreads();  // tile 0 staged (drains prologue loads)

  for (int tile = 0; tile < SS / 64; ++tile) {
    const int cur = tile & 1;

    // prefetch next tile into the other buffer; its latency hides under this
    // tile's compute, and the END-of-iter barrier drains it (cheap by then).
    if (tile + 1 < SS / 64) stage(tile + 1, cur ^ 1);

    const u16* Ks = SMEM + cur * 8192;  // u16 idx: 16384 B per buffer
    const u16* Vs = Ks + 4096;

    // S^T = K Q^T: c2[qq][t][r] = P[key = t*32+16*(r>>3)+8*kh+4*((r>>2)&1)+(r&3)][q]
    // One ak read feeds both qq MFMA.
    f32x16 c2[2][2] = {};
#pragma unroll
    for (int ks = 0; ks < 4; ++ks) {
#pragma unroll
      for (int tt = 0; tt < 2; ++tt) {
        int jr = tt * 32 + p31;
        int slot = (ks * 2 + kh) ^ sK0 ^ (tt << 2);
        bf16x8 ak = *(const bf16x8*)(Ks + jr * 64 + slot * 8);
        c2[0][tt] = __builtin_amdgcn_mfma_f32_32x32x16_bf16(ak, aq[0][ks], c2[0][tt], 0, 0, 0);
        c2[1][tt] = __builtin_amdgcn_mfma_f32_32x32x16_bf16(ak, aq[1][ks], c2[1][tt], 0, 0, 0);
      }
    }

    // P = 2^s in place; per-lane partial l per qq
#pragma unroll
    for (int qq = 0; qq < 2; ++qq)
#pragma unroll
      for (int tt = 0; tt < 2; ++tt)
#pragma unroll
        for (int r = 0; r < 16; ++r)
          c2[qq][tt][r] = EXP2(c2[qq][tt][r]);
    {
      float s0 = 0.f, s1 = 0.f;
#pragma unroll
      for (int r = 0; r < 16; ++r) { s0 += c2[0][0][r]; s0 += c2[0][1][r]; }
#pragma unroll
      for (int r = 0; r < 16; ++r) { s1 += c2[1][0][r]; s1 += c2[1][1][r]; }
      l_p0 += s0; l_p1 += s1;
    }

    // pack P^T B-frags fully in-register: bp[qq][2t+hf].elem[j] = c2[qq][t][8*hf+j]
    union { uint32_t u[4]; bf16x8 b; } bp[2][4];
#pragma unroll
    for (int qq = 0; qq < 2; ++qq)
#pragma unroll
      for (int tt = 0; tt < 2; ++tt)
#pragma unroll
        for (int hf = 0; hf < 2; ++hf)
#pragma unroll
          for (int i = 0; i < 4; ++i)
            bp[qq][tt * 2 + hf].u[i] =
                cvtpk(c2[qq][tt][hf * 8 + 2 * i], c2[qq][tt][hf * 8 + 2 * i + 1]);

    // O^T += V^T P^T  (A = V^T rows = d; one av read feeds both qq MFMA)
#pragma unroll
    for (int ks = 0; ks < 4; ++ks) {
#pragma unroll
      for (int dt = 0; dt < 2; ++dt) {
        int vr = dt * 32 + l31;
        int slot = (ks * 2 + kh) ^ sV0 ^ (dt << 2);
        bf16x8 av = *(const bf16x8*)(Vs + vr * 64 + slot * 8);
        ot[0][dt] = __builtin_amdgcn_mfma_f32_32x32x16_bf16(av, bp[0][ks].b, ot[0][dt], 0, 0, 0);
        ot[1][dt] = __builtin_amdgcn_mfma_f32_32x32x16_bf16(av, bp[1][ks].b, ot[1][dt], 0, 0, 0);
      }
    }

    // single barrier: drains the prefetch (issued a compute-phase ago, so
    // cheap) AND protects buf[cur] before iter t+1 stages into it.
    __syncthreads();
  }

  // epilogue: l across the two kh halves (lanes l, l+32 share q)
  l_p0 += __shfl_xor(l_p0, 32, 64);
  l_p1 += __shfl_xor(l_p1, 32, 64);
  const float inv_l0 = 1.0f / l_p0;
  const float inv_l1 = 1.0f / l_p1;

  // normalize + stage O^T -> Es[256 q][72] (reused SMEM; wave-local rows)
  u16* Es = SMEM;
#pragma unroll
  for (int qq = 0; qq < 2; ++qq) {
    const float il = qq ? inv_l1 : inv_l0;
#pragma unroll
    for (int dt = 0; dt < 2; ++dt)
#pragma unroll
      for (int rq = 0; rq < 4; ++rq) {
        u16x4 pv;
#pragma unroll
        for (int i = 0; i < 4; ++i) pv[i] = bfbits(ot[qq][dt][rq * 4 + i] * il);
        *(u16x4*)(Es + (w * 64 + qq * 32 + l31) * 72 + dt * 32 + rq * 8 + kh * 4) = pv;
      }
  }

  const int rr = lane >> 3;  // 0..7
  const int cc8 = lane & 7;  // 16B chunk
#pragma unroll
  for (int p = 0; p < 8; ++p) {
    int row = w * 64 + p * 8 + rr;
    u16x8 vv = *(const u16x8*)(Es + row * 72 + cc8 * 8);
    *(u16x8*)(ctx + (size_t)(b * SS + q0 + row) * DD + h * DH + cc8 * 8) = vv;
  }
}

extern "C" void kernel_launch(void* const* d_in, const int* in_sizes, int n_in,
                              void* d_out, int out_size, void* d_ws, size_t ws_size,
                              hipStream_t stream) {
  (void)in_sizes; (void)n_in; (void)out_size; (void)ws_size;
  const float* x = (const float*)d_in[0];
  const float* WQ = (const float*)d_in[1];
  const float* WK = (const float*)d_in[2];
  const float* WV = (const float*)d_in[3];
  const float* WO = (const float*)d_in[4];

  char* ws = (char*)d_ws;
  u16* xb = (u16*)ws;            ws += (size_t)8192 * 1024 * 2;   // 16.8 MB (reused as ctx)
  u16* wcat = (u16*)ws;          ws += (size_t)3072 * 1024 * 2;   // 6.3 MB
  u16* wot = (u16*)ws;           ws += (size_t)1024 * 1024 * 2;   // 2.1 MB
  u16* qkv = (u16*)ws;           ws += (size_t)8192 * 3072 * 2;   // 50.3 MB
  u16* vt = (u16*)ws;            ws += (size_t)BB * HD * DH * SS * 2;  // 16.8 MB
  u16* ctx = xb;  // x consumed by QKV GEMM before attention writes ctx

  // 1/sqrt(1024) * log2(e): softmax runs in exp2 domain with scale folded into WQ
  const float QSCALE = 0.03125f * 1.4426950408889634f;

  prep_kernel<<<dim3(9216), dim3(256), 0, stream>>>(x, xb, WQ, WK, WV, WO, wcat, wot, QSCALE);

  gemm_nt_kernel<1><<<dim3(24, 64), dim3(256), 0, stream>>>(xb, wcat, (void*)qkv, 8192, 3072, 1024);
  vtrans_kernel<<<dim3(32, 16, 4), dim3(256), 0, stream>>>(qkv, vt);
  attn_kernel<<<dim3(8, 16, 4), dim3(256), 0, stream>>>(qkv, vt, ctx);
  gemm_nt_kernel<0><<<dim3(8, 64), dim3(256), 0, stream>>>(ctx, wot, d_out, 8192, 1024, 1024);
}

// Round 12
// 247.331 us; speedup vs baseline: 1.1008x; 1.0478x over previous
//
#include <hip/hip_runtime.h>
#include <stdint.h>

typedef unsigned short u16;
typedef __bf16 bf16x8 __attribute__((ext_vector_type(8)));
typedef float f32x4 __attribute__((ext_vector_type(4)));
typedef float f32x16 __attribute__((ext_vector_type(16)));
typedef unsigned short u16x8 __attribute__((ext_vector_type(8)));
typedef unsigned short u16x4 __attribute__((ext_vector_type(4)));

#define HD 16
#define BB 4
#define SS 2048
#define DD 1024
#define DH 64

#if __has_builtin(__builtin_amdgcn_exp2f)
#define EXP2(x) __builtin_amdgcn_exp2f(x)
#else
#define EXP2(x) exp2f(x)
#endif

__device__ __forceinline__ u16 f2bf(float f) {
  union { float f; uint32_t u; } v; v.f = f;
  uint32_t u = v.u;
  return (u16)((u + 0x7FFFu + ((u >> 16) & 1u)) >> 16);  // RNE, no NaN in data
}

// native converter for hot paths (single v_cvt, RNE)
__device__ __forceinline__ u16 bfbits(float f) {
  union { __bf16 h; u16 u; } c;
  c.h = (__bf16)f;
  return c.u;
}

// pack two f32 -> u32 of 2 bf16 (lo = first arg), single instruction.
__device__ __forceinline__ uint32_t cvtpk(float lo, float hi) {
  uint32_t r;
  asm("v_cvt_pk_bf16_f32 %0, %1, %2" : "=v"(r) : "v"(lo), "v"(hi));
  return r;
}

__device__ __forceinline__ void gl2lds16(const void* g, void* l) {
  __builtin_amdgcn_global_load_lds(
      (const __attribute__((address_space(1))) void*)g,
      (__attribute__((address_space(3))) void*)l, 16, 0, 0);
}

// -------- fused prep: cast x (8192 blocks) + transpose 4 weights (1024 blocks) --------
__global__ __launch_bounds__(256) void prep_kernel(const float* __restrict__ x,
                                                   u16* __restrict__ xb,
                                                   const float* __restrict__ WQ,
                                                   const float* __restrict__ WK,
                                                   const float* __restrict__ WV,
                                                   const float* __restrict__ WO,
                                                   u16* __restrict__ wcat,
                                                   u16* __restrict__ wot, float qscale) {
  __shared__ u16 tile[64][65];
  const int bid = blockIdx.x;
  const int t = threadIdx.x;
  if (bid < 8192) {
    int i = bid * 256 + t;  // n4 = 2097152 = 8192*256 exactly
    float4 v = ((const float4*)x)[i];
    u16x4 o;
    o.x = f2bf(v.x); o.y = f2bf(v.y); o.z = f2bf(v.z); o.w = f2bf(v.w);
    ((u16x4*)xb)[i] = o;
    return;
  }
  const int id2 = bid - 8192;
  const int z = id2 >> 8;
  const float* src = (z == 0) ? WQ : (z == 1) ? WK : (z == 2) ? WV : WO;
  u16* dst = (z < 3) ? wcat + (size_t)z * 1024 * 1024 : wot;
  const float scale = (z == 0) ? qscale : 1.0f;
  const int bx = (id2 & 15) * 64;         // src col (n)
  const int by = ((id2 >> 4) & 15) * 64;  // src row (k)
  const int c = t & 63, r0 = t >> 6;
#pragma unroll
  for (int r = r0; r < 64; r += 4)
    tile[r][c] = f2bf(src[(size_t)(by + r) * 1024 + bx + c] * scale);
  __syncthreads();
#pragma unroll
  for (int r = r0; r < 64; r += 4)
    dst[(size_t)(bx + r) * 1024 + by + c] = tile[c][r];
}

// ------------- V transpose: qkv[b*S+s][2048 + h*64 + d] -> vt[((b*16+h)*64+d)][s] -------------
__global__ __launch_bounds__(256) void vtrans_kernel(const u16* __restrict__ qkv,
                                                     u16* __restrict__ vt) {
  __shared__ u16 tile[64][65];
  const int s0 = blockIdx.x * 64;
  const int h = blockIdx.y;
  const int b = blockIdx.z;
  const int t = threadIdx.x;
  const int c = t & 63, r0 = t >> 6;
#pragma unroll
  for (int r = r0; r < 64; r += 4)
    tile[r][c] = qkv[(size_t)(b * SS + s0 + r) * 3072 + 2048 + h * DH + c];
  __syncthreads();
#pragma unroll
  for (int r = r0; r < 64; r += 4)
    vt[((size_t)(b * HD + h) * DH + r) * SS + s0 + c] = tile[c][r];
}

// ---------------- NT GEMM, BK=64, 128x128 tile, 32x32x16 MFMA ----------------
// R22: body = R18/R21 exact (proven best). NEW: bijective XCD-chunk block
// swizzle (T1). Default round-robin dispatch makes every XCD's 4MB L2 hold
// the WHOLE B panel (QKV: 6.3MB, re-read 64x) -> thrash -> the 786MB staging
// stream is L3-served (~80us). MODE 0 (QKV, grid 24x64): each XCD owns a
// 6x-col x 32y-row chunk: B slice 1.6MB + active A rows L2-resident; ext
// traffic ~786->~77MB. MODE 1 (AO, grid 8x64): y-stripe of 8 rows: A 2MB +
// B 2.1MB both resident; 262->~34MB. Assumes linear x-fastest round-robin
// dispatch (guide T1); wrong assumption = perf-neutral, never incorrect.
template <int OUT_BF16, int MODE>
__global__ __launch_bounds__(256) void gemm_nt_kernel(const u16* __restrict__ A,
                                                      const u16* __restrict__ Bt,
                                                      void* __restrict__ Cv,
                                                      int M, int N, int K) {
  __shared__ __attribute__((aligned(16))) u16 As[128 * 64];  // 16 KB
  __shared__ __attribute__((aligned(16))) u16 Bs[128 * 64];  // 16 KB
  const int t = threadIdx.x;
  const int lane = t & 63;
  const int w = t >> 6;

  int bx, by;
  if (MODE == 0) {  // QKV: grid (24,64); 8 XCD chunks of 6 cols x 32 rows
    int lid = blockIdx.y * 24 + blockIdx.x;
    int xcd = lid & 7, idx = lid >> 3;          // idx in [0,192)
    bx = (xcd & 3) * 6 + idx % 6;               // 6 same-row blocks consecutive
    by = (xcd >> 2) * 32 + idx / 6;
  } else {          // AO: grid (8,64); 8 XCD y-stripes of 8 rows
    int lid = blockIdx.y * 8 + blockIdx.x;
    int xcd = lid & 7, idx = lid >> 3;          // idx in [0,64)
    by = xcd * 8 + (idx & 7);
    bx = idx >> 3;
  }
  const int m0 = by * 128;
  const int n0 = bx * 128;

  f32x16 acc[2][2] = {};

  const int srow = t >> 3;            // staging row within pass (0..31)
  const int cpos = t & 7;             // chunk slot 0..7
  const int scc = cpos ^ (srow & 7);  // XOR-swizzled chunk (pass-invariant)
  const int wm = (w >> 1) * 64;
  const int wn = (w & 1) * 64;
  const int l31 = lane & 31;
  const int kh = lane >> 5;  // 0/1: which 8-wide k-half of the 16-wide instr K

  for (int k0 = 0; k0 < K; k0 += 64) {
#pragma unroll
    for (int p = 0; p < 4; ++p) {
      int row = p * 32 + srow;
      gl2lds16(A + (size_t)(m0 + row) * K + k0 + scc * 8, (char*)As + p * 4096 + w * 1024);
      gl2lds16(Bt + (size_t)(n0 + row) * K + k0 + scc * 8, (char*)Bs + p * 4096 + w * 1024);
    }
    __syncthreads();

#pragma unroll
    for (int ks = 0; ks < 4; ++ks) {  // 4 x K=16
      bf16x8 af[2], bfr[2];
#pragma unroll
      for (int i = 0; i < 2; ++i) {
        int ra = wm + i * 32 + l31;
        af[i] = *(const bf16x8*)(As + ra * 64 + (((ks * 2 + kh) ^ (ra & 7)) * 8));
        int rb = wn + i * 32 + l31;
        bfr[i] = *(const bf16x8*)(Bs + rb * 64 + (((ks * 2 + kh) ^ (rb & 7)) * 8));
      }
#pragma unroll
      for (int i = 0; i < 2; ++i)
#pragma unroll
        for (int j = 0; j < 2; ++j)
          acc[i][j] = __builtin_amdgcn_mfma_f32_32x32x16_bf16(af[i], bfr[j], acc[i][j], 0, 0, 0);
    }
    __syncthreads();
  }

#pragma unroll
  for (int i = 0; i < 2; ++i)
#pragma unroll
    for (int j = 0; j < 2; ++j)
#pragma unroll
      for (int rg = 0; rg < 16; ++rg) {
        int gr = m0 + wm + i * 32 + (rg & 3) + ((rg >> 2) * 8) + 4 * kh;
        int gc = n0 + wn + j * 32 + l31;
        float v = acc[i][j][rg];
        if (OUT_BF16)
          ((u16*)Cv)[(size_t)gr * N + gc] = f2bf(v);
        else
          ((float*)Cv)[(size_t)gr * N + gc] = v;
      }
}

// ---------------- flash attention: per (qtile256, h, b) ----------------
// R18 body FROZEN (70.4 us, ~89% combined issue). R22 adds only the XCD
// (h,b)-grouping swizzle: all 8 q-blocks of one head land on one XCD so K/V
// (0.5MB per (h,b)) is fetched once per XCD instead of 8x. Direct observable:
// FETCH_SIZE 139MB -> ~60-90MB.
__global__ __launch_bounds__(256, 2) void attn_kernel(const u16* __restrict__ qkv,
                                                      const u16* __restrict__ vt,
                                                      u16* __restrict__ ctx) {
  // dbuf layout (bytes): buf s at s*16384: K[64][64] @ +0, V^T[64][64] @ +8192.
  // Epilogue reuses SMEM as Es[256][72] = 36864 B.
  __shared__ __attribute__((aligned(16))) u16 SMEM[18432];  // 36.9 KB

  const int t = threadIdx.x;
  const int lane = t & 63;
  const int w = t >> 6;

  // XCD swizzle: grid (8,16,4) = 512 blocks; XCD k owns combos [8k,8k+8) of
  // (z*16+y), each with its 8 q-blocks contiguous. Bijective.
  const int lid = (blockIdx.z * 16 + blockIdx.y) * 8 + blockIdx.x;
  const int xcd = lid & 7, idx = lid >> 3;       // idx in [0,64)
  const int combo = xcd * 8 + (idx >> 3);        // (h,b) combo
  const int q0 = (idx & 7) * 256;
  const int h = combo & 15;
  const int b = combo >> 4;

  const int srow = t >> 3;  // staging row (0..31 per pass)
  const int cpos = t & 7;
  const size_t qkv_row0 = (size_t)(b * SS) * 3072;
  const size_t vtbase = ((size_t)(b * HD + h) * DH) * SS;

  const int l31 = lane & 31;
  const int kh = lane >> 5;
  // pi: swap bits 2<->3 (C-row rho -> key), so regs line up as PV B-frags
  const int p31 = (l31 & 19) | ((l31 & 4) << 1) | ((l31 & 8) >> 1);
  // per-lane sigma bases (tt/dt add ^4 via the r>>5 term)
  const int sK0 = (p31 & 3) | ((((p31 >> 2) ^ (p31 >> 3)) & 1) << 2);
  const int sV0 = (l31 & 3) | ((((l31 >> 2) ^ (l31 >> 3)) & 1) << 2);

  // stage tile (64 keys at tile*64) into buffer bufsel (4 gl2lds per wave).
  auto stage = [&](int tile, int bufsel) {
    char* Kb = (char*)SMEM + bufsel * 16384;
    const int kk0 = tile * 64;
#pragma unroll
    for (int p = 0; p < 2; ++p) {
      int r = p * 32 + srow;
      int sg = (r & 3) | ((((r >> 2) ^ (r >> 3) ^ (r >> 5)) & 1) << 2);
      int cc = cpos ^ sg;
      gl2lds16(qkv + qkv_row0 + (size_t)(kk0 + r) * 3072 + 1024 + h * DH + cc * 8,
               Kb + p * 4096 + w * 1024);
      gl2lds16(vt + vtbase + (size_t)r * SS + kk0 + cc * 8,
               Kb + 8192 + p * 4096 + w * 1024);
    }
  };

  stage(0, 0);  // prologue: tile 0 -> buf 0

  // Q frags (loaded once): q = q0 + w*64 + qq*32 + l31, d = ks*16 + kh*8 + {0..7}.
  // WQ carries 1/sqrt(D)*log2(e).
  bf16x8 aq[2][4];
#pragma unroll
  for (int qq = 0; qq < 2; ++qq)
#pragma unroll
    for (int ks = 0; ks < 4; ++ks)
      aq[qq][ks] = *(const bf16x8*)(qkv + qkv_row0 +
                                    (size_t)(q0 + w * 64 + qq * 32 + l31) * 3072 +
                                    h * DH + ks * 16 + kh * 8);

  f32x16 ot[2][2] = {};          // ot[qq][dt][r]: d = dt*32+(r&3)+8*(r>>2)+4*kh
  float l_p0 = 0.f, l_p1 = 0.f;  // per-lane partial sum of 2^s, per qq

  __syncthreads();  // tile 0 staged (drains prologue loads)

  for (int tile = 0; tile < SS / 64; ++tile) {
    const int cur = tile & 1;

    // prefetch next tile into the other buffer; its latency hides under this
    // tile's compute, and the END-of-iter barrier drains it (cheap by then).
    if (tile + 1 < SS / 64) stage(tile + 1, cur ^ 1);

    const u16* Ks = SMEM + cur * 8192;  // u16 idx: 16384 B per buffer
    const u16* Vs = Ks + 4096;

    // S^T = K Q^T: c2[qq][t][r] = P[key = t*32+16*(r>>3)+8*kh+4*((r>>2)&1)+(r&3)][q]
    // One ak read feeds both qq MFMA.
    f32x16 c2[2][2] = {};
#pragma unroll
    for (int ks = 0; ks < 4; ++ks) {
#pragma unroll
      for (int tt = 0; tt < 2; ++tt) {
        int jr = tt * 32 + p31;
        int slot = (ks * 2 + kh) ^ sK0 ^ (tt << 2);
        bf16x8 ak = *(const bf16x8*)(Ks + jr * 64 + slot * 8);
        c2[0][tt] = __builtin_amdgcn_mfma_f32_32x32x16_bf16(ak, aq[0][ks], c2[0][tt], 0, 0, 0);
        c2[1][tt] = __builtin_amdgcn_mfma_f32_32x32x16_bf16(ak, aq[1][ks], c2[1][tt], 0, 0, 0);
      }
    }

    // P = 2^s in place; per-lane partial l per qq
#pragma unroll
    for (int qq = 0; qq < 2; ++qq)
#pragma unroll
      for (int tt = 0; tt < 2; ++tt)
#pragma unroll
        for (int r = 0; r < 16; ++r)
          c2[qq][tt][r] = EXP2(c2[qq][tt][r]);
    {
      float s0 = 0.f, s1 = 0.f;
#pragma unroll
      for (int r = 0; r < 16; ++r) { s0 += c2[0][0][r]; s0 += c2[0][1][r]; }
#pragma unroll
      for (int r = 0; r < 16; ++r) { s1 += c2[1][0][r]; s1 += c2[1][1][r]; }
      l_p0 += s0; l_p1 += s1;
    }

    // pack P^T B-frags fully in-register: bp[qq][2t+hf].elem[j] = c2[qq][t][8*hf+j]
    union { uint32_t u[4]; bf16x8 b; } bp[2][4];
#pragma unroll
    for (int qq = 0; qq < 2; ++qq)
#pragma unroll
      for (int tt = 0; tt < 2; ++tt)
#pragma unroll
        for (int hf = 0; hf < 2; ++hf)
#pragma unroll
          for (int i = 0; i < 4; ++i)
            bp[qq][tt * 2 + hf].u[i] =
                cvtpk(c2[qq][tt][hf * 8 + 2 * i], c2[qq][tt][hf * 8 + 2 * i + 1]);

    // O^T += V^T P^T  (A = V^T rows = d; one av read feeds both qq MFMA)
#pragma unroll
    for (int ks = 0; ks < 4; ++ks) {
#pragma unroll
      for (int dt = 0; dt < 2; ++dt) {
        int vr = dt * 32 + l31;
        int slot = (ks * 2 + kh) ^ sV0 ^ (dt << 2);
        bf16x8 av = *(const bf16x8*)(Vs + vr * 64 + slot * 8);
        ot[0][dt] = __builtin_amdgcn_mfma_f32_32x32x16_bf16(av, bp[0][ks].b, ot[0][dt], 0, 0, 0);
        ot[1][dt] = __builtin_amdgcn_mfma_f32_32x32x16_bf16(av, bp[1][ks].b, ot[1][dt], 0, 0, 0);
      }
    }

    // single barrier: drains the prefetch (issued a compute-phase ago, so
    // cheap) AND protects buf[cur] before iter t+1 stages into it.
    __syncthreads();
  }

  // epilogue: l across the two kh halves (lanes l, l+32 share q)
  l_p0 += __shfl_xor(l_p0, 32, 64);
  l_p1 += __shfl_xor(l_p1, 32, 64);
  const float inv_l0 = 1.0f / l_p0;
  const float inv_l1 = 1.0f / l_p1;

  // normalize + stage O^T -> Es[256 q][72] (reused SMEM; wave-local rows)
  u16* Es = SMEM;
#pragma unroll
  for (int qq = 0; qq < 2; ++qq) {
    const float il = qq ? inv_l1 : inv_l0;
#pragma unroll
    for (int dt = 0; dt < 2; ++dt)
#pragma unroll
      for (int rq = 0; rq < 4; ++rq) {
        u16x4 pv;
#pragma unroll
        for (int i = 0; i < 4; ++i) pv[i] = bfbits(ot[qq][dt][rq * 4 + i] * il);
        *(u16x4*)(Es + (w * 64 + qq * 32 + l31) * 72 + dt * 32 + rq * 8 + kh * 4) = pv;
      }
  }

  const int rr = lane >> 3;  // 0..7
  const int cc8 = lane & 7;  // 16B chunk
#pragma unroll
  for (int p = 0; p < 8; ++p) {
    int row = w * 64 + p * 8 + rr;
    u16x8 vv = *(const u16x8*)(Es + row * 72 + cc8 * 8);
    *(u16x8*)(ctx + (size_t)(b * SS + q0 + row) * DD + h * DH + cc8 * 8) = vv;
  }
}

extern "C" void kernel_launch(void* const* d_in, const int* in_sizes, int n_in,
                              void* d_out, int out_size, void* d_ws, size_t ws_size,
                              hipStream_t stream) {
  (void)in_sizes; (void)n_in; (void)out_size; (void)ws_size;
  const float* x = (const float*)d_in[0];
  const float* WQ = (const float*)d_in[1];
  const float* WK = (const float*)d_in[2];
  const float* WV = (const float*)d_in[3];
  const float* WO = (const float*)d_in[4];

  char* ws = (char*)d_ws;
  u16* xb = (u16*)ws;            ws += (size_t)8192 * 1024 * 2;   // 16.8 MB (reused as ctx)
  u16* wcat = (u16*)ws;          ws += (size_t)3072 * 1024 * 2;   // 6.3 MB
  u16* wot = (u16*)ws;           ws += (size_t)1024 * 1024 * 2;   // 2.1 MB
  u16* qkv = (u16*)ws;           ws += (size_t)8192 * 3072 * 2;   // 50.3 MB
  u16* vt = (u16*)ws;            ws += (size_t)BB * HD * DH * SS * 2;  // 16.8 MB
  u16* ctx = xb;  // x consumed by QKV GEMM before attention writes ctx

  // 1/sqrt(1024) * log2(e): softmax runs in exp2 domain with scale folded into WQ
  const float QSCALE = 0.03125f * 1.4426950408889634f;

  prep_kernel<<<dim3(9216), dim3(256), 0, stream>>>(x, xb, WQ, WK, WV, WO, wcat, wot, QSCALE);

  gemm_nt_kernel<1, 0><<<dim3(24, 64), dim3(256), 0, stream>>>(xb, wcat, (void*)qkv, 8192, 3072, 1024);
  vtrans_kernel<<<dim3(32, 16, 4), dim3(256), 0, stream>>>(qkv, vt);
  attn_kernel<<<dim3(8, 16, 4), dim3(256), 0, stream>>>(qkv, vt, ctx);
  gemm_nt_kernel<0, 1><<<dim3(8, 64), dim3(256), 0, stream>>>(ctx, wot, d_out, 8192, 1024, 1024);
}